// Round 2
// baseline (345.059 us; speedup 1.0000x reference)
//
#include <hip/hip_runtime.h>
#include <hip/hip_bf16.h>

#define N_NODES 100000
#define N_EDGES 1600000
#define D 128
#define NBUCKETS 3125         // 100000 / 32 exactly, bucket = 32 rows (row >> 5)
#define HCAP 720              // fixed slab per bucket (mean 512, sigma 22.6, +9.2s)

typedef float          floatx4 __attribute__((ext_vector_type(4)));
typedef __bf16         bf16x8  __attribute__((ext_vector_type(8)));
typedef unsigned short ushort8 __attribute__((ext_vector_type(8)));

__device__ __forceinline__ unsigned rotl32(unsigned x, int d) {
    return (x << d) | (x >> (32 - d));
}

// JAX threefry2x32 with key (0, 42)
__device__ __forceinline__ void threefry_0_42(unsigned c0, unsigned c1,
                                              unsigned& o0, unsigned& o1) {
    const unsigned k0 = 0u, k1 = 42u;
    const unsigned k2 = 0x1BD11BDAu ^ k0 ^ k1;
    unsigned x0 = c0 + k0;
    unsigned x1 = c1 + k1;
#define TF_R4(r0, r1, r2, r3)                      \
    x0 += x1; x1 = rotl32(x1, r0); x1 ^= x0;       \
    x0 += x1; x1 = rotl32(x1, r1); x1 ^= x0;       \
    x0 += x1; x1 = rotl32(x1, r2); x1 ^= x0;       \
    x0 += x1; x1 = rotl32(x1, r3); x1 ^= x0;
    TF_R4(13, 15, 26, 6);  x0 += k1; x1 += k2 + 1u;
    TF_R4(17, 29, 16, 24); x0 += k2; x1 += k0 + 2u;
    TF_R4(13, 15, 26, 6);  x0 += k0; x1 += k1 + 3u;
    TF_R4(17, 29, 16, 24); x0 += k1; x1 += k2 + 4u;
    TF_R4(13, 15, 26, 6);  x0 += k2; x1 += k0 + 5u;
#undef TF_R4
    o0 = x0; o1 = x1;
}

__device__ __forceinline__ bool keep_elem(unsigned i) {
    unsigned o0, o1;
    threefry_0_42(0u, i, o0, o1);
    return (((o0 ^ o1) >> 31) == 0u);
}

__device__ __forceinline__ unsigned short f32_bf16(float f) {
    unsigned u = __float_as_uint(f);
    u += 0x7fffu + ((u >> 16) & 1u);   // RNE
    return (unsigned short)(u >> 16);
}

// ---------------- Phase 1: fused dropout + GEMM (bf16 MFMA) ----------------
__global__ __launch_bounds__(256)
void k_gemm(const float* __restrict__ x, const float* __restrict__ W,
            unsigned short* __restrict__ hb) {
    __shared__ __align__(16) unsigned short Wt[128][136];  // Wt[n][k] = bf16(W[k][n])
    __shared__ __align__(16) unsigned short xs[32][136];

    const int t = threadIdx.x;
    const int g = blockIdx.x;

    {
        int n      = t & 127;
        int k8base = t >> 7;
#pragma unroll
        for (int it = 0; it < 8; ++it) {
            int k8 = (it * 2 + k8base) * 8;
            unsigned short tmp[8];
#pragma unroll
            for (int j = 0; j < 8; ++j)
                tmp[j] = f32_bf16(W[(k8 + j) * 128 + n]);
            *(ushort8*)&Wt[n][k8] = *(ushort8*)tmp;
        }
    }
    {
        int m  = t >> 4;
        int c0 = (t & 15) * 8;
        int r0 = g * 32 + m;
        const float* pa = x + r0 * D + c0;
        const float* pb = x + (r0 + 16) * D + c0;
        float va[8], vb[8];
        *(float4*)&va[0] = ((const float4*)pa)[0];
        *(float4*)&va[4] = ((const float4*)pa)[1];
        *(float4*)&vb[0] = ((const float4*)pb)[0];
        *(float4*)&vb[4] = ((const float4*)pb)[1];
        int ibase = r0 * D + c0;
        unsigned short ta[8], tb[8];
#pragma unroll
        for (int j = 0; j < 8; ++j) {
            float fa = keep_elem((unsigned)(ibase + j))        ? 2.0f * va[j] : 0.0f;
            float fb = keep_elem((unsigned)(ibase + 2048 + j)) ? 2.0f * vb[j] : 0.0f;
            ta[j] = f32_bf16(fa);
            tb[j] = f32_bf16(fb);
        }
        *(ushort8*)&xs[m][c0]      = *(ushort8*)ta;
        *(ushort8*)&xs[16 + m][c0] = *(ushort8*)tb;
    }
    __syncthreads();

    const int w  = t >> 6;
    const int l  = t & 63;
    const int rt = w >> 1;
    const int ctbase = (w & 1) * 4;
    const int mm = l & 15;
    const int q  = l >> 4;
    const int koff = q * 8;
    const unsigned short* xrow = &xs[rt * 16 + mm][0];
    const int growbase = g * 32 + rt * 16;

    for (int ci = 0; ci < 4; ++ci) {
        int ct = ctbase + ci;
        const unsigned short* wrow = &Wt[ct * 16 + mm][0];
        floatx4 acc = {0.f, 0.f, 0.f, 0.f};
#pragma unroll
        for (int kt = 0; kt < 4; ++kt) {
            bf16x8 a = *(const bf16x8*)(xrow + kt * 32 + koff);
            bf16x8 b = *(const bf16x8*)(wrow + kt * 32 + koff);
            acc = __builtin_amdgcn_mfma_f32_16x16x32_bf16(a, b, acc, 0, 0, 0);
        }
        int col = ct * 16 + mm;
#pragma unroll
        for (int reg = 0; reg < 4; ++reg) {
            int grow = growbase + q * 4 + reg;
            hb[grow * D + col] = f32_bf16(acc[reg]);
        }
    }
}

// ---------------- Phase 2: single-pass bucketing into fixed slabs ----------------
// bucket b = rows [32b, 32b+32), slab buf[b*HCAP .. b*HCAP+cnt[b])
// entry.x = (col << 7) | (rowlow << 24), entry.y = float bits of val
__global__ __launch_bounds__(256)
void k_bucket(const int* __restrict__ row, const int* __restrict__ col,
              const float* __restrict__ val, int* __restrict__ cnt,
              int2* __restrict__ buf) {
    int e4 = (blockIdx.x * 256 + threadIdx.x) * 4;
    if (e4 >= N_EDGES) return;
    int4   r = *(const int4*)(row + e4);
    int4   c = *(const int4*)(col + e4);
    float4 v = *(const float4*)(val + e4);

    int   rr[4] = {r.x, r.y, r.z, r.w};
    int   cc[4] = {c.x, c.y, c.z, c.w};
    float vv[4] = {v.x, v.y, v.z, v.w};
#pragma unroll
    for (int j = 0; j < 4; ++j) {
        int b   = rr[j] >> 5;
        int pos = atomicAdd(&cnt[b], 1);
        if (pos < HCAP) {
            int2 ent;
            ent.x = (cc[j] << 7) | ((rr[j] & 31) << 24);
            ent.y = __float_as_int(vv[j]);
            buf[b * HCAP + pos] = ent;
        }
    }
}

// ---------------- Phase 3: per-bucket sort + gather + ReLU ----------------
// Block b owns bucket b = rows [32b, 32b+32). Entries register-staged,
// counting-sorted into one small LDS buffer, then gathered with deep ILP.
__global__ __launch_bounds__(256, 8)
void k_sortgather(const int* __restrict__ cnt, const int2* __restrict__ buf,
                  const unsigned short* __restrict__ hb, float* __restrict__ out) {
    __shared__ __align__(16) int2 ents2[HCAP];
    __shared__ int cnt_[32];
    __shared__ int scan_[32];
    __shared__ int cur_[32];

    const int b = blockIdx.x, t = threadIdx.x;
    const int2* slab = buf + b * HCAP;
    int n = cnt[b];
    if (n > HCAP) n = HCAP;

    if (t < 32) cnt_[t] = 0;
    __syncthreads();

    // stage entries into registers + LDS histogram (<=3 per thread, HCAP=720)
    int2 er[3];
    int  rl_[3];
#pragma unroll
    for (int k = 0; k < 3; ++k) {
        int i = k * 256 + t;
        if (i < n) {
            er[k]  = slab[i];
            rl_[k] = (unsigned)er[k].x >> 24;
            atomicAdd(&cnt_[rl_[k]], 1);
        } else {
            rl_[k] = -1;
        }
    }
    __syncthreads();

    // single-wave inclusive scan over 32 rowlow counters
    if (t < 32) {
        int v = cnt_[t];
        int x = v;
#pragma unroll
        for (int off = 1; off < 32; off <<= 1) {
            int u = __shfl_up(x, off);
            if (t >= off) x += u;
        }
        scan_[t] = x;
        cur_[t]  = x - v;   // exclusive start
    }
    __syncthreads();

    // counting-sort scatter (regs -> LDS)
#pragma unroll
    for (int k = 0; k < 3; ++k) {
        if (rl_[k] >= 0) {
            int pos = atomicAdd(&cur_[rl_[k]], 1);
            ents2[pos] = er[k];
        }
    }
    __syncthreads();

    // gather: wave w -> rowlows [8w, 8w+8); lane -> cols l2, l2+1
    const int w  = t >> 6;
    const int l2 = (t & 63) * 2;
    const unsigned short* hbl = hb + l2;
    for (int r = 0; r < 8; ++r) {
        int rl = w * 8 + r;
        int c  = cnt_[rl];
        int b0 = scan_[rl] - c;
        float a0 = 0.f, a1 = 0.f;
        int i = 0;
        for (; i + 16 <= c; i += 16) {
            unsigned ex[16];
            float    vv[16];
#pragma unroll
            for (int j = 0; j < 16; ++j) {
                int2 e = ents2[b0 + i + j];
                ex[j] = (unsigned)e.x & 0xFFFFFFu;   // col*128 (halfword offset)
                vv[j] = __int_as_float(e.y);
            }
            unsigned hv[16];
#pragma unroll
            for (int j = 0; j < 16; ++j)
                hv[j] = *(const unsigned*)(hbl + ex[j]);
#pragma unroll
            for (int j = 0; j < 16; ++j) {
                a0 = fmaf(vv[j], __uint_as_float(hv[j] << 16), a0);
                a1 = fmaf(vv[j], __uint_as_float(hv[j] & 0xffff0000u), a1);
            }
        }
        for (; i + 4 <= c; i += 4) {
            unsigned ex[4];
            float    vv[4];
#pragma unroll
            for (int j = 0; j < 4; ++j) {
                int2 e = ents2[b0 + i + j];
                ex[j] = (unsigned)e.x & 0xFFFFFFu;
                vv[j] = __int_as_float(e.y);
            }
            unsigned hv[4];
#pragma unroll
            for (int j = 0; j < 4; ++j)
                hv[j] = *(const unsigned*)(hbl + ex[j]);
#pragma unroll
            for (int j = 0; j < 4; ++j) {
                a0 = fmaf(vv[j], __uint_as_float(hv[j] << 16), a0);
                a1 = fmaf(vv[j], __uint_as_float(hv[j] & 0xffff0000u), a1);
            }
        }
        for (; i < c; ++i) {
            int2 e = ents2[b0 + i];
            float v = __int_as_float(e.y);
            unsigned hv = *(const unsigned*)(hbl + ((unsigned)e.x & 0xFFFFFFu));
            a0 = fmaf(v, __uint_as_float(hv << 16), a0);
            a1 = fmaf(v, __uint_as_float(hv & 0xffff0000u), a1);
        }
        int grow = (b << 5) + rl;   // always < N_NODES (3125*32 = 100000)
        float2 rr;
        rr.x = a0 > 0.f ? a0 : 0.f;
        rr.y = a1 > 0.f ? a1 : 0.f;
        *(float2*)(out + grow * D + l2) = rr;
    }
}

extern "C" void kernel_launch(void* const* d_in, const int* in_sizes, int n_in,
                              void* d_out, int out_size, void* d_ws, size_t ws_size,
                              hipStream_t stream) {
    const float* x    = (const float*)d_in[0];
    const float* W    = (const float*)d_in[1];
    const int*   arow = (const int*)d_in[2];
    const int*   acol = (const int*)d_in[3];
    const float* aval = (const float*)d_in[4];
    float* out = (float*)d_out;

    char* ws = (char*)d_ws;
    unsigned short* hb = (unsigned short*)ws;            // 25,600,000 B
    size_t off = 25600000;
    int* cnt  = (int*)(ws + off); off += 12544;          // NBUCKETS ints (12.5 KB)
    int2* buf = (int2*)(ws + off); off += (size_t)NBUCKETS * HCAP * 8;  // 18 MB slabs
    // total ~43.6 MB

    hipMemsetAsync(cnt, 0, NBUCKETS * 4, stream);
    k_bucket     <<<(N_EDGES / 4 + 255) / 256, 256, 0, stream>>>(arow, acol, aval, cnt, buf);
    k_gemm       <<<3125, 256, 0, stream>>>(x, W, hb);
    k_sortgather <<<NBUCKETS, 256, 0, stream>>>(cnt, buf, hb, out);
}

// Round 3
// 229.431 us; speedup vs baseline: 1.5040x; 1.5040x over previous
//
#include <hip/hip_runtime.h>
#include <hip/hip_bf16.h>

#define N_NODES 100000
#define N_EDGES 1600000
#define D 128
#define NC 391                // coarse buckets, 256 rows each (row >> 8)
#define CCAP 5120             // coarse slab cap (mean 4096, sigma 64, +16s)
#define NF 3125               // fine buckets, 32 rows each
#define FCAP 640              // fine sub-slab cap (mean 512, sigma 22.6, +5.7s)
#define C1S 32                // cnt1 stride in ints (128B line padding)

typedef float          floatx4 __attribute__((ext_vector_type(4)));
typedef __bf16         bf16x8  __attribute__((ext_vector_type(8)));
typedef unsigned short ushort8 __attribute__((ext_vector_type(8)));

__device__ __forceinline__ unsigned rotl32(unsigned x, int d) {
    return (x << d) | (x >> (32 - d));
}

// JAX threefry2x32 with key (0, 42)
__device__ __forceinline__ void threefry_0_42(unsigned c0, unsigned c1,
                                              unsigned& o0, unsigned& o1) {
    const unsigned k0 = 0u, k1 = 42u;
    const unsigned k2 = 0x1BD11BDAu ^ k0 ^ k1;
    unsigned x0 = c0 + k0;
    unsigned x1 = c1 + k1;
#define TF_R4(r0, r1, r2, r3)                      \
    x0 += x1; x1 = rotl32(x1, r0); x1 ^= x0;       \
    x0 += x1; x1 = rotl32(x1, r1); x1 ^= x0;       \
    x0 += x1; x1 = rotl32(x1, r2); x1 ^= x0;       \
    x0 += x1; x1 = rotl32(x1, r3); x1 ^= x0;
    TF_R4(13, 15, 26, 6);  x0 += k1; x1 += k2 + 1u;
    TF_R4(17, 29, 16, 24); x0 += k2; x1 += k0 + 2u;
    TF_R4(13, 15, 26, 6);  x0 += k0; x1 += k1 + 3u;
    TF_R4(17, 29, 16, 24); x0 += k1; x1 += k2 + 4u;
    TF_R4(13, 15, 26, 6);  x0 += k2; x1 += k0 + 5u;
#undef TF_R4
    o0 = x0; o1 = x1;
}

__device__ __forceinline__ bool keep_elem(unsigned i) {
    unsigned o0, o1;
    threefry_0_42(0u, i, o0, o1);
    return (((o0 ^ o1) >> 31) == 0u);
}

__device__ __forceinline__ unsigned short f32_bf16(float f) {
    unsigned u = __float_as_uint(f);
    u += 0x7fffu + ((u >> 16) & 1u);   // RNE
    return (unsigned short)(u >> 16);
}

// ---------------- Phase 1: fused dropout + GEMM (bf16 MFMA) ----------------
__global__ __launch_bounds__(256)
void k_gemm(const float* __restrict__ x, const float* __restrict__ W,
            unsigned short* __restrict__ hb) {
    __shared__ __align__(16) unsigned short Wt[128][136];  // Wt[n][k] = bf16(W[k][n])
    __shared__ __align__(16) unsigned short xs[32][136];

    const int t = threadIdx.x;
    const int g = blockIdx.x;

    {
        int n      = t & 127;
        int k8base = t >> 7;
#pragma unroll
        for (int it = 0; it < 8; ++it) {
            int k8 = (it * 2 + k8base) * 8;
            unsigned short tmp[8];
#pragma unroll
            for (int j = 0; j < 8; ++j)
                tmp[j] = f32_bf16(W[(k8 + j) * 128 + n]);
            *(ushort8*)&Wt[n][k8] = *(ushort8*)tmp;
        }
    }
    {
        int m  = t >> 4;
        int c0 = (t & 15) * 8;
        int r0 = g * 32 + m;
        const float* pa = x + r0 * D + c0;
        const float* pb = x + (r0 + 16) * D + c0;
        float va[8], vb[8];
        *(float4*)&va[0] = ((const float4*)pa)[0];
        *(float4*)&va[4] = ((const float4*)pa)[1];
        *(float4*)&vb[0] = ((const float4*)pb)[0];
        *(float4*)&vb[4] = ((const float4*)pb)[1];
        int ibase = r0 * D + c0;
        unsigned short ta[8], tb[8];
#pragma unroll
        for (int j = 0; j < 8; ++j) {
            float fa = keep_elem((unsigned)(ibase + j))        ? 2.0f * va[j] : 0.0f;
            float fb = keep_elem((unsigned)(ibase + 2048 + j)) ? 2.0f * vb[j] : 0.0f;
            ta[j] = f32_bf16(fa);
            tb[j] = f32_bf16(fb);
        }
        *(ushort8*)&xs[m][c0]      = *(ushort8*)ta;
        *(ushort8*)&xs[16 + m][c0] = *(ushort8*)tb;
    }
    __syncthreads();

    const int w  = t >> 6;
    const int l  = t & 63;
    const int rt = w >> 1;
    const int ctbase = (w & 1) * 4;
    const int mm = l & 15;
    const int q  = l >> 4;
    const int koff = q * 8;
    const unsigned short* xrow = &xs[rt * 16 + mm][0];
    const int growbase = g * 32 + rt * 16;

    for (int ci = 0; ci < 4; ++ci) {
        int ct = ctbase + ci;
        const unsigned short* wrow = &Wt[ct * 16 + mm][0];
        floatx4 acc = {0.f, 0.f, 0.f, 0.f};
#pragma unroll
        for (int kt = 0; kt < 4; ++kt) {
            bf16x8 a = *(const bf16x8*)(xrow + kt * 32 + koff);
            bf16x8 b = *(const bf16x8*)(wrow + kt * 32 + koff);
            acc = __builtin_amdgcn_mfma_f32_16x16x32_bf16(a, b, acc, 0, 0, 0);
        }
        int col = ct * 16 + mm;
#pragma unroll
        for (int reg = 0; reg < 4; ++reg) {
            int grow = growbase + q * 4 + reg;
            hb[grow * D + col] = f32_bf16(acc[reg]);
        }
    }
}

// ---------------- Phase 2a: coarse scatter (256-row buckets, LDS-privatized) --------
// entry.x = (col << 7) | (rowlow8 << 24), entry.y = float bits of val
__global__ __launch_bounds__(256)
void k_bucket1(const int* __restrict__ row, const int* __restrict__ col,
               const float* __restrict__ val, int* __restrict__ cnt1,
               int2* __restrict__ buf) {
    __shared__ int h[NC];
    __shared__ int lbase[NC];
    const int t = threadIdx.x;
    for (int i = t; i < NC; i += 256) h[i] = 0;
    __syncthreads();

    int rows[16], cols[16];
    float vals[16];
    int base = blockIdx.x * 4096;
#pragma unroll
    for (int k = 0; k < 4; ++k) {
        int e4 = base + (k * 256 + t) * 4;
        if (e4 < N_EDGES) {
            *(int4*)&rows[k * 4]   = *(const int4*)(row + e4);
            *(int4*)&cols[k * 4]   = *(const int4*)(col + e4);
            *(float4*)&vals[k * 4] = *(const float4*)(val + e4);
        } else {
            rows[k * 4] = rows[k * 4 + 1] = rows[k * 4 + 2] = rows[k * 4 + 3] = -1;
        }
    }
#pragma unroll
    for (int j = 0; j < 16; ++j)
        if (rows[j] >= 0) atomicAdd(&h[rows[j] >> 8], 1);
    __syncthreads();

    // reserve ranges: one padded global counter per coarse bucket (own 128B line)
    for (int i = t; i < NC; i += 256) {
        int c = h[i];
        lbase[i] = c ? atomicAdd(&cnt1[i * C1S], c) : 0;
    }
    __syncthreads();
    for (int i = t; i < NC; i += 256) h[i] = 0;
    __syncthreads();

#pragma unroll
    for (int j = 0; j < 16; ++j) {
        if (rows[j] >= 0) {
            int bb  = rows[j] >> 8;
            int pos = lbase[bb] + atomicAdd(&h[bb], 1);
            if (pos < CCAP) {
                int2 ent;
                ent.x = (cols[j] << 7) | ((rows[j] & 255) << 24);
                ent.y = __float_as_int(vals[j]);
                buf[bb * CCAP + pos] = ent;
            }
        }
    }
}

// ---------------- Phase 2b: in-place split into 8 fine sub-slabs ----------------
// Block c owns coarse slab c exclusively: reads all entries to registers,
// counting-sorts by rowlow8>>5 into sub-slabs [f*FCAP, f*FCAP+cnt2). No global atomics.
__global__ __launch_bounds__(512)
void k_split(const int* __restrict__ cnt1, int2* __restrict__ buf,
             int* __restrict__ cnt2) {
    __shared__ int h[8][9];      // per-wave histogram (padded)
    __shared__ int cur[8][9];    // per-wave scatter cursors

    const int c = blockIdx.x, t = threadIdx.x, w = t >> 6;
    int n = cnt1[c * C1S];
    if (n > CCAP) n = CCAP;
    int2* slab = buf + c * CCAP;

    if (t < 72) ((int*)h)[t] = 0;
    __syncthreads();

    int2 er[10];
    int  bin[10];
#pragma unroll
    for (int k = 0; k < 10; ++k) {
        int i = k * 512 + t;
        if (i < n) {
            er[k]  = slab[i];
            bin[k] = ((unsigned)er[k].x) >> 29;   // top 3 bits of rowlow8
            atomicAdd(&h[w][bin[k]], 1);
        } else {
            bin[k] = -1;
        }
    }
    __syncthreads();

    // per-bin: prefix over waves -> wave bases; total -> cnt2
    if (t < 8) {
        int s = 0;
#pragma unroll
        for (int wv = 0; wv < 8; ++wv) {
            cur[wv][t] = s;
            s += h[wv][t];
        }
        cnt2[c * 8 + t] = s;      // cnt2 sized 3136, extra entries harmless
    }
    __syncthreads();
    if (t < 64) {
        int wv = t >> 3, b = t & 7;
        cur[wv][b] += b * FCAP;   // add fine sub-slab origin
    }
    __syncthreads();

    // scatter back in place (all reads completed before this barrier)
#pragma unroll
    for (int k = 0; k < 10; ++k) {
        if (bin[k] >= 0) {
            int pos = atomicAdd(&cur[w][bin[k]], 1);
            if (pos < (bin[k] + 1) * FCAP)   // drop fine-overflow (P ~ 1e-5)
                slab[pos] = er[k];
        }
    }
}

// ---------------- Phase 3: per-fine-bucket sort + gather + ReLU ----------------
__global__ __launch_bounds__(256, 8)
void k_sortgather(const int* __restrict__ cnt2, const int2* __restrict__ buf,
                  const unsigned short* __restrict__ hb, float* __restrict__ out) {
    __shared__ __align__(16) int2 ents2[FCAP];
    __shared__ int cnt_[32];
    __shared__ int scan_[32];
    __shared__ int cur_[32];

    const int b = blockIdx.x, t = threadIdx.x;
    const int2* slab = buf + (b >> 3) * CCAP + (b & 7) * FCAP;
    int n = cnt2[b];
    if (n > FCAP) n = FCAP;

    if (t < 32) cnt_[t] = 0;
    __syncthreads();

    // stage entries into registers + LDS histogram (<=3 per thread, FCAP=640)
    int2 er[3];
    int  rl_[3];
#pragma unroll
    for (int k = 0; k < 3; ++k) {
        int i = k * 256 + t;
        if (i < n) {
            er[k]  = slab[i];
            rl_[k] = ((unsigned)er[k].x >> 24) & 31;
            atomicAdd(&cnt_[rl_[k]], 1);
        } else {
            rl_[k] = -1;
        }
    }
    __syncthreads();

    // single-wave inclusive scan over 32 rowlow counters
    if (t < 32) {
        int v = cnt_[t];
        int x = v;
#pragma unroll
        for (int off = 1; off < 32; off <<= 1) {
            int u = __shfl_up(x, off);
            if (t >= off) x += u;
        }
        scan_[t] = x;
        cur_[t]  = x - v;   // exclusive start
    }
    __syncthreads();

    // counting-sort scatter (regs -> LDS)
#pragma unroll
    for (int k = 0; k < 3; ++k) {
        if (rl_[k] >= 0) {
            int pos = atomicAdd(&cur_[rl_[k]], 1);
            ents2[pos] = er[k];
        }
    }
    __syncthreads();

    // gather: wave w -> rowlows [8w, 8w+8); lane -> cols l2, l2+1
    const int w  = t >> 6;
    const int l2 = (t & 63) * 2;
    const unsigned short* hbl = hb + l2;
    for (int r = 0; r < 8; ++r) {
        int rl = w * 8 + r;
        int c  = cnt_[rl];
        int b0 = scan_[rl] - c;
        float a0 = 0.f, a1 = 0.f;
        int i = 0;
        for (; i + 16 <= c; i += 16) {
            unsigned ex[16];
            float    vv[16];
#pragma unroll
            for (int j = 0; j < 16; ++j) {
                int2 e = ents2[b0 + i + j];
                ex[j] = (unsigned)e.x & 0xFFFFFFu;   // col*128 (halfword offset)
                vv[j] = __int_as_float(e.y);
            }
            unsigned hv[16];
#pragma unroll
            for (int j = 0; j < 16; ++j)
                hv[j] = *(const unsigned*)(hbl + ex[j]);
#pragma unroll
            for (int j = 0; j < 16; ++j) {
                a0 = fmaf(vv[j], __uint_as_float(hv[j] << 16), a0);
                a1 = fmaf(vv[j], __uint_as_float(hv[j] & 0xffff0000u), a1);
            }
        }
        for (; i + 4 <= c; i += 4) {
            unsigned ex[4];
            float    vv[4];
#pragma unroll
            for (int j = 0; j < 4; ++j) {
                int2 e = ents2[b0 + i + j];
                ex[j] = (unsigned)e.x & 0xFFFFFFu;
                vv[j] = __int_as_float(e.y);
            }
            unsigned hv[4];
#pragma unroll
            for (int j = 0; j < 4; ++j)
                hv[j] = *(const unsigned*)(hbl + ex[j]);
#pragma unroll
            for (int j = 0; j < 4; ++j) {
                a0 = fmaf(vv[j], __uint_as_float(hv[j] << 16), a0);
                a1 = fmaf(vv[j], __uint_as_float(hv[j] & 0xffff0000u), a1);
            }
        }
        for (; i < c; ++i) {
            int2 e = ents2[b0 + i];
            float v = __int_as_float(e.y);
            unsigned hv = *(const unsigned*)(hbl + ((unsigned)e.x & 0xFFFFFFu));
            a0 = fmaf(v, __uint_as_float(hv << 16), a0);
            a1 = fmaf(v, __uint_as_float(hv & 0xffff0000u), a1);
        }
        int grow = (b << 5) + rl;   // always < N_NODES (3125*32 = 100000)
        float2 rr;
        rr.x = a0 > 0.f ? a0 : 0.f;
        rr.y = a1 > 0.f ? a1 : 0.f;
        *(float2*)(out + grow * D + l2) = rr;
    }
}

extern "C" void kernel_launch(void* const* d_in, const int* in_sizes, int n_in,
                              void* d_out, int out_size, void* d_ws, size_t ws_size,
                              hipStream_t stream) {
    const float* x    = (const float*)d_in[0];
    const float* W    = (const float*)d_in[1];
    const int*   arow = (const int*)d_in[2];
    const int*   acol = (const int*)d_in[3];
    const float* aval = (const float*)d_in[4];
    float* out = (float*)d_out;

    char* ws = (char*)d_ws;
    unsigned short* hb = (unsigned short*)ws;            // 25,600,000 B
    size_t off = 25600000;
    int* cnt1 = (int*)(ws + off); off += NC * C1S * 4;   // 50,048 B (padded counters)
    off = (off + 127) & ~(size_t)127;
    int* cnt2 = (int*)(ws + off); off += 3136 * 4;       // 12,544 B
    off = (off + 127) & ~(size_t)127;
    int2* buf = (int2*)(ws + off); off += (size_t)NC * CCAP * 8;  // 16.0 MB
    // total ~41.7 MB

    hipMemsetAsync(cnt1, 0, NC * C1S * 4, stream);
    k_bucket1    <<<NC, 256, 0, stream>>>(arow, acol, aval, cnt1, buf);
    k_split      <<<NC, 512, 0, stream>>>(cnt1, buf, cnt2);
    k_gemm       <<<3125, 256, 0, stream>>>(x, W, hb);
    k_sortgather <<<NF, 256, 0, stream>>>(cnt2, buf, hb, out);
}

// Round 4
// 222.468 us; speedup vs baseline: 1.5510x; 1.0313x over previous
//
#include <hip/hip_runtime.h>
#include <hip/hip_bf16.h>

#define N_NODES 100000
#define N_EDGES 1600000
#define D 128
#define NC 391                // coarse buckets, 256 rows each (row >> 8)
#define CCAP 5120             // coarse slab cap (mean 4096, sigma 64, +16s)
#define NF 3125               // fine buckets, 32 rows each
#define C1S 32                // cnt1 stride in ints (128B line padding)
#define RSS 257               // row-start stride per coarse bucket
#define GCAP 1024             // fine-group LDS cap (mean 512, sigma 22.6, +22s)
#define GEMM_H1 1563          // gemm blocks in launch 1
#define GEMM_H2 1562          // gemm blocks in launch 2

typedef float          floatx4 __attribute__((ext_vector_type(4)));
typedef __bf16         bf16x8  __attribute__((ext_vector_type(8)));
typedef unsigned short ushort8 __attribute__((ext_vector_type(8)));

__device__ __forceinline__ unsigned rotl32(unsigned x, int d) {
    return (x << d) | (x >> (32 - d));
}

// JAX threefry2x32 with key (0, 42)
__device__ __forceinline__ void threefry_0_42(unsigned c0, unsigned c1,
                                              unsigned& o0, unsigned& o1) {
    const unsigned k0 = 0u, k1 = 42u;
    const unsigned k2 = 0x1BD11BDAu ^ k0 ^ k1;
    unsigned x0 = c0 + k0;
    unsigned x1 = c1 + k1;
#define TF_R4(r0, r1, r2, r3)                      \
    x0 += x1; x1 = rotl32(x1, r0); x1 ^= x0;       \
    x0 += x1; x1 = rotl32(x1, r1); x1 ^= x0;       \
    x0 += x1; x1 = rotl32(x1, r2); x1 ^= x0;       \
    x0 += x1; x1 = rotl32(x1, r3); x1 ^= x0;
    TF_R4(13, 15, 26, 6);  x0 += k1; x1 += k2 + 1u;
    TF_R4(17, 29, 16, 24); x0 += k2; x1 += k0 + 2u;
    TF_R4(13, 15, 26, 6);  x0 += k0; x1 += k1 + 3u;
    TF_R4(17, 29, 16, 24); x0 += k1; x1 += k2 + 4u;
    TF_R4(13, 15, 26, 6);  x0 += k2; x1 += k0 + 5u;
#undef TF_R4
    o0 = x0; o1 = x1;
}

__device__ __forceinline__ bool keep_elem(unsigned i) {
    unsigned o0, o1;
    threefry_0_42(0u, i, o0, o1);
    return (((o0 ^ o1) >> 31) == 0u);
}

__device__ __forceinline__ unsigned short f32_bf16(float f) {
    unsigned u = __float_as_uint(f);
    u += 0x7fffu + ((u >> 16) & 1u);   // RNE
    return (unsigned short)(u >> 16);
}

// ---------------- gemm tile body (32 rows per block) ----------------
__device__ __forceinline__ void gemm_body(const float* __restrict__ x,
                                          const float* __restrict__ W,
                                          unsigned short* __restrict__ hb,
                                          unsigned short (*Wt)[136],
                                          unsigned short (*xs)[136],
                                          int g, int t) {
    {
        int n      = t & 127;
        int k8base = t >> 7;
#pragma unroll
        for (int it = 0; it < 8; ++it) {
            int k8 = (it * 2 + k8base) * 8;
            unsigned short tmp[8];
#pragma unroll
            for (int j = 0; j < 8; ++j)
                tmp[j] = f32_bf16(W[(k8 + j) * 128 + n]);
            *(ushort8*)&Wt[n][k8] = *(ushort8*)tmp;
        }
    }
    {
        int m  = t >> 4;
        int c0 = (t & 15) * 8;
        int r0 = g * 32 + m;
        const float* pa = x + r0 * D + c0;
        const float* pb = x + (r0 + 16) * D + c0;
        float va[8], vb[8];
        *(float4*)&va[0] = ((const float4*)pa)[0];
        *(float4*)&va[4] = ((const float4*)pa)[1];
        *(float4*)&vb[0] = ((const float4*)pb)[0];
        *(float4*)&vb[4] = ((const float4*)pb)[1];
        int ibase = r0 * D + c0;
        unsigned short ta[8], tb[8];
#pragma unroll
        for (int j = 0; j < 8; ++j) {
            float fa = keep_elem((unsigned)(ibase + j))        ? 2.0f * va[j] : 0.0f;
            float fb = keep_elem((unsigned)(ibase + 2048 + j)) ? 2.0f * vb[j] : 0.0f;
            ta[j] = f32_bf16(fa);
            tb[j] = f32_bf16(fb);
        }
        *(ushort8*)&xs[m][c0]      = *(ushort8*)ta;
        *(ushort8*)&xs[16 + m][c0] = *(ushort8*)tb;
    }
    __syncthreads();

    const int w  = t >> 6;
    const int l  = t & 63;
    const int rt = w >> 1;
    const int ctbase = (w & 1) * 4;
    const int mm = l & 15;
    const int q  = l >> 4;
    const int koff = q * 8;
    const unsigned short* xrow = &xs[rt * 16 + mm][0];
    const int growbase = g * 32 + rt * 16;

    for (int ci = 0; ci < 4; ++ci) {
        int ct = ctbase + ci;
        const unsigned short* wrow = &Wt[ct * 16 + mm][0];
        floatx4 acc = {0.f, 0.f, 0.f, 0.f};
#pragma unroll
        for (int kt = 0; kt < 4; ++kt) {
            bf16x8 a = *(const bf16x8*)(xrow + kt * 32 + koff);
            bf16x8 b = *(const bf16x8*)(wrow + kt * 32 + koff);
            acc = __builtin_amdgcn_mfma_f32_16x16x32_bf16(a, b, acc, 0, 0, 0);
        }
        int col = ct * 16 + mm;
#pragma unroll
        for (int reg = 0; reg < 4; ++reg) {
            int grow = growbase + q * 4 + reg;
            hb[grow * D + col] = f32_bf16(acc[reg]);
        }
    }
}

// ---------------- Launch 1: coarse scatter (blocks 0..NC-1) + gemm half A ----------
// entry.x = (col << 7) | (rowlow8 << 24), entry.y = float bits of val
__global__ __launch_bounds__(256)
void k_p1(const float* __restrict__ x, const float* __restrict__ W,
          unsigned short* __restrict__ hb,
          const int* __restrict__ row, const int* __restrict__ col,
          const float* __restrict__ val, int* __restrict__ cnt1,
          int2* __restrict__ buf) {
    __shared__ __align__(16) unsigned short Wt[128][136];
    __shared__ __align__(16) unsigned short xs[32][136];
    __shared__ int h[NC];
    __shared__ int lbase[NC];

    const int t = threadIdx.x;
    if (blockIdx.x >= NC) {
        gemm_body(x, W, hb, Wt, xs, blockIdx.x - NC, t);
        return;
    }

    // ---- bucket1 ----
    for (int i = t; i < NC; i += 256) h[i] = 0;
    __syncthreads();

    int rows[16], cols[16];
    float vals[16];
    int base = blockIdx.x * 4096;
#pragma unroll
    for (int k = 0; k < 4; ++k) {
        int e4 = base + (k * 256 + t) * 4;
        if (e4 < N_EDGES) {
            *(int4*)&rows[k * 4]   = *(const int4*)(row + e4);
            *(int4*)&cols[k * 4]   = *(const int4*)(col + e4);
            *(float4*)&vals[k * 4] = *(const float4*)(val + e4);
        } else {
            rows[k * 4] = rows[k * 4 + 1] = rows[k * 4 + 2] = rows[k * 4 + 3] = -1;
        }
    }
#pragma unroll
    for (int j = 0; j < 16; ++j)
        if (rows[j] >= 0) atomicAdd(&h[rows[j] >> 8], 1);
    __syncthreads();

    // reserve ranges: one padded global counter per coarse bucket (own 128B line)
    for (int i = t; i < NC; i += 256) {
        int c = h[i];
        lbase[i] = c ? atomicAdd(&cnt1[i * C1S], c) : 0;
    }
    __syncthreads();
    for (int i = t; i < NC; i += 256) h[i] = 0;
    __syncthreads();

#pragma unroll
    for (int j = 0; j < 16; ++j) {
        if (rows[j] >= 0) {
            int bb  = rows[j] >> 8;
            int pos = lbase[bb] + atomicAdd(&h[bb], 1);
            if (pos < CCAP) {
                int2 ent;
                ent.x = (cols[j] << 7) | ((rows[j] & 255) << 24);
                ent.y = __float_as_int(vals[j]);
                buf[bb * CCAP + pos] = ent;
            }
        }
    }
}

// ---------------- Launch 2: full row-sort of coarse slabs (blocks 0..NC-1) + gemm half B ----
// In-place 256-bin counting sort by rowlow8; emits per-row start offsets rs[].
__global__ __launch_bounds__(256)
void k_p2(const float* __restrict__ x, const float* __restrict__ W,
          unsigned short* __restrict__ hb,
          const int* __restrict__ cnt1, int2* __restrict__ buf,
          int* __restrict__ rs) {
    __shared__ __align__(16) unsigned short Wt[128][136];
    __shared__ __align__(16) unsigned short xs[32][136];
    __shared__ int h[4][256];
    __shared__ int wsum[4];

    const int t = threadIdx.x;
    if (blockIdx.x >= NC) {
        gemm_body(x, W, hb, Wt, xs, blockIdx.x - NC + GEMM_H1, t);
        return;
    }

    // ---- split/sort ----
    const int c = blockIdx.x;
    const int w = t >> 6;
    int n = cnt1[c * C1S];
    if (n > CCAP) n = CCAP;
    int2* slab = buf + c * CCAP;

    for (int i = t; i < 1024; i += 256) ((int*)h)[i] = 0;
    __syncthreads();

    // read everything to registers + per-wave histogram (20 entries/thread)
    int2 er[20];
#pragma unroll
    for (int k = 0; k < 20; ++k) {
        int i = k * 256 + t;
        if (i < n) {
            er[k] = slab[i];
            atomicAdd(&h[w][((unsigned)er[k].x) >> 24], 1);
        }
    }
    __syncthreads();

    // bin totals -> block-wide exclusive scan (bin index = t)
    int v = h[0][t] + h[1][t] + h[2][t] + h[3][t];
    int xsc = v;
#pragma unroll
    for (int off = 1; off < 64; off <<= 1) {
        int u = __shfl_up(xsc, off);
        if ((t & 63) >= off) xsc += u;
    }
    if ((t & 63) == 63) wsum[t >> 6] = xsc;
    __syncthreads();
    int wo = 0;
    for (int k = 0; k < (t >> 6); ++k) wo += wsum[k];
    int basex = xsc - v + wo;               // exclusive prefix = row start
    rs[c * RSS + t] = basex;
    if (t == 0) rs[c * RSS + 256] = n;
    // convert per-wave histograms into scatter cursors
    int s = basex;
#pragma unroll
    for (int wv = 0; wv < 4; ++wv) {
        int tmp = h[wv][t];
        h[wv][t] = s;
        s += tmp;
    }
    __syncthreads();

    // in-place scatter (all reads completed before the barrier)
#pragma unroll
    for (int k = 0; k < 20; ++k) {
        int i = k * 256 + t;
        if (i < n) {
            int pos = atomicAdd(&h[w][((unsigned)er[k].x) >> 24], 1);
            slab[pos] = er[k];
        }
    }
}

// ---------------- Launch 3: pure gather + ReLU (entries pre-sorted by row) ----------
__global__ __launch_bounds__(256, 8)
void k_gather(const int* __restrict__ rs, const int2* __restrict__ buf,
              const unsigned short* __restrict__ hb, float* __restrict__ out) {
    __shared__ __align__(16) int2 eL[GCAP];

    const int b = blockIdx.x, t = threadIdx.x;
    const int c = b >> 3;
    const int2* slab = buf + c * CCAP;
    const int* rsb = rs + c * RSS + (b & 7) * 32;
    const int rs0 = rsb[0];
    int nf = rsb[32] - rs0;
    if (nf > GCAP) nf = GCAP;    // statistically unreachable (+22 sigma)

    for (int i = t; i < nf; i += 256) eL[i] = slab[rs0 + i];
    __syncthreads();

    // wave w -> rowlows [8w, 8w+8); lane -> cols l2, l2+1
    const int w  = t >> 6;
    const int l2 = (t & 63) * 2;
    const unsigned short* hbl = hb + l2;
    for (int r = 0; r < 8; ++r) {
        int rl = w * 8 + r;
        int s0 = rsb[rl] - rs0;
        int e0 = rsb[rl + 1] - rs0;
        if (e0 > nf) e0 = nf;
        int cc = e0 - s0;
        float a0 = 0.f, a1 = 0.f;
        int i = 0;
        for (; i + 16 <= cc; i += 16) {
            unsigned ex[16];
            float    vv[16];
#pragma unroll
            for (int j = 0; j < 16; ++j) {
                int2 e = eL[s0 + i + j];
                ex[j] = (unsigned)e.x & 0xFFFFFFu;   // col*128 (halfword offset)
                vv[j] = __int_as_float(e.y);
            }
            unsigned hv[16];
#pragma unroll
            for (int j = 0; j < 16; ++j)
                hv[j] = *(const unsigned*)(hbl + ex[j]);
#pragma unroll
            for (int j = 0; j < 16; ++j) {
                a0 = fmaf(vv[j], __uint_as_float(hv[j] << 16), a0);
                a1 = fmaf(vv[j], __uint_as_float(hv[j] & 0xffff0000u), a1);
            }
        }
        for (; i + 4 <= cc; i += 4) {
            unsigned ex[4];
            float    vv[4];
#pragma unroll
            for (int j = 0; j < 4; ++j) {
                int2 e = eL[s0 + i + j];
                ex[j] = (unsigned)e.x & 0xFFFFFFu;
                vv[j] = __int_as_float(e.y);
            }
            unsigned hv[4];
#pragma unroll
            for (int j = 0; j < 4; ++j)
                hv[j] = *(const unsigned*)(hbl + ex[j]);
#pragma unroll
            for (int j = 0; j < 4; ++j) {
                a0 = fmaf(vv[j], __uint_as_float(hv[j] << 16), a0);
                a1 = fmaf(vv[j], __uint_as_float(hv[j] & 0xffff0000u), a1);
            }
        }
        for (; i < cc; ++i) {
            int2 e = eL[s0 + i];
            float v = __int_as_float(e.y);
            unsigned hv = *(const unsigned*)(hbl + ((unsigned)e.x & 0xFFFFFFu));
            a0 = fmaf(v, __uint_as_float(hv << 16), a0);
            a1 = fmaf(v, __uint_as_float(hv & 0xffff0000u), a1);
        }
        int grow = (b << 5) + rl;   // always < N_NODES (3125*32 = 100000)
        float2 rr;
        rr.x = a0 > 0.f ? a0 : 0.f;
        rr.y = a1 > 0.f ? a1 : 0.f;
        *(float2*)(out + grow * D + l2) = rr;
    }
}

extern "C" void kernel_launch(void* const* d_in, const int* in_sizes, int n_in,
                              void* d_out, int out_size, void* d_ws, size_t ws_size,
                              hipStream_t stream) {
    const float* x    = (const float*)d_in[0];
    const float* W    = (const float*)d_in[1];
    const int*   arow = (const int*)d_in[2];
    const int*   acol = (const int*)d_in[3];
    const float* aval = (const float*)d_in[4];
    float* out = (float*)d_out;

    char* ws = (char*)d_ws;
    unsigned short* hb = (unsigned short*)ws;            // 25,600,000 B
    size_t off = 25600000;
    int* cnt1 = (int*)(ws + off); off += NC * C1S * 4;   // 50,048 B (padded counters)
    off = (off + 127) & ~(size_t)127;
    int* rs   = (int*)(ws + off); off += NC * RSS * 4;   // 401,948 B row starts
    off = (off + 127) & ~(size_t)127;
    int2* buf = (int2*)(ws + off); off += (size_t)NC * CCAP * 8;  // 16.0 MB
    // total ~42.1 MB

    hipMemsetAsync(cnt1, 0, NC * C1S * 4, stream);
    k_p1     <<<NC + GEMM_H1, 256, 0, stream>>>(x, W, hb, arow, acol, aval, cnt1, buf);
    k_p2     <<<NC + GEMM_H2, 256, 0, stream>>>(x, W, hb, cnt1, buf, rs);
    k_gather <<<NF, 256, 0, stream>>>(rs, buf, hb, out);
}